// Round 1
// baseline (810.533 us; speedup 1.0000x reference)
//
#include <hip/hip_runtime.h>
#include <math.h>

#define Bn 4
#define Sn 8192
#define Dn 768
#define NSUB 4096
#define EG 32768

// ---- workspace layout (bytes) ----
#define OFF_COUNTS   0
#define OFF_OFFSETS  (8*NSUB*4)
#define OFF_POS      (2*8*NSUB*4)
#define OFF_DINV     (3*8*NSUB*4)
#define OFF_CSR      (4*8*NSUB*4)
#define OFF_XW       (OFF_CSR + 8*EG*4)   // 1.5 MB, 16B aligned

__device__ __forceinline__ void fma4(float4& a, float w, const float4& v){
    a.x = fmaf(w, v.x, a.x); a.y = fmaf(w, v.y, a.y);
    a.z = fmaf(w, v.z, a.z); a.w = fmaf(w, v.w, a.w);
}

__global__ __launch_bounds__(256) void k_zero(int* __restrict__ p, int n){
    int i = blockIdx.x*256 + threadIdx.x;
    if (i < n) p[i] = 0;
}

__global__ __launch_bounds__(256) void k_copy(const float4* __restrict__ in,
                                              float4* __restrict__ out, int n4){
    int stride = gridDim.x*256;
    for (int i = blockIdx.x*256 + threadIdx.x; i < n4; i += stride) out[i] = in[i];
}

// count in-degree (dst) per graph; gi = g*4 + b
__global__ __launch_bounds__(256) void k_count(const int* __restrict__ eie,
                                               const int* __restrict__ ein,
                                               int* __restrict__ counts){
    int gi = blockIdx.z; int g = gi >> 2, b = gi & 3;
    const int* dst = (g ? ein : eie) + ((size_t)b*2 + 1)*EG;
    int* c = counts + gi*NSUB;
    for (int e = blockIdx.x*256 + threadIdx.x; e < EG; e += gridDim.x*256)
        atomicAdd(&c[dst[e]], 1);
}

// exclusive scan of counts -> offsets (+pos copy), dinv = (deg+1)^-0.5
__global__ __launch_bounds__(256) void k_scan(const int* __restrict__ counts,
                                              int* __restrict__ offsets,
                                              int* __restrict__ pos,
                                              float* __restrict__ dinv){
    int gi = blockIdx.x;
    int t  = threadIdx.x;
    __shared__ int part[256];
    const int* c = counts + gi*NSUB;
    int loc[16]; int s = 0;
    int base = t*16;
    #pragma unroll
    for (int j=0;j<16;j++){ loc[j] = s; s += c[base+j]; }
    part[t] = s;
    __syncthreads();
    for (int off=1; off<256; off<<=1){
        int v = 0;
        if (t >= off) v = part[t-off];
        __syncthreads();
        if (t >= off) part[t] += v;
        __syncthreads();
    }
    int prefix = (t==0) ? 0 : part[t-1];
    #pragma unroll
    for (int j=0;j<16;j++){
        int o = prefix + loc[j];
        offsets[gi*NSUB + base + j] = o;
        pos[gi*NSUB + base + j]     = o;
        dinv[gi*NSUB + base + j]    = 1.0f / sqrtf((float)(c[base+j] + 1)); // +1 self-loop
    }
}

// counting-sort edges into CSR by dst
__global__ __launch_bounds__(256) void k_fill(const int* __restrict__ eie,
                                              const int* __restrict__ ein,
                                              int* __restrict__ pos,
                                              int* __restrict__ csr){
    int gi = blockIdx.z; int g = gi >> 2, b = gi & 3;
    const int* ei = (g ? ein : eie) + (size_t)b*2*EG;
    int* p  = pos + gi*NSUB;
    int* cs = csr + (size_t)gi*EG;
    for (int e = blockIdx.x*256 + threadIdx.x; e < EG; e += gridDim.x*256){
        int src = ei[e], d = ei[EG + e];
        int q = atomicAdd(&p[d], 1);
        cs[q] = src;
    }
}

// xw[slot][i][:] = t[b][map[i]][:] @ W  — gather-fused fp32 GEMM, 128x128 tile, BK=16
__global__ __launch_bounds__(256) void k_gemm(const float* __restrict__ T,
                                              const int* __restrict__ t2e,
                                              const int* __restrict__ t2n,
                                              const float* __restrict__ We,
                                              const float* __restrict__ Wn,
                                              float* __restrict__ xw, int gi0){
    int z = blockIdx.z; int gi = gi0 + z;
    int g = gi >> 2, b = gi & 3;
    const int*   map = (g ? t2n : t2e) + b*NSUB;
    const float* W   = g ? Wn : We;
    const float* X   = T + (size_t)b*Sn*Dn;
    float*       O   = xw + (size_t)z*NSUB*Dn;

    int bm = blockIdx.x * 128;
    int bn = blockIdx.y * 128;
    __shared__ float As[16][132];
    __shared__ float Bs[16][132];
    __shared__ int   rows[128];
    int tid = threadIdx.x;
    if (tid < 128) rows[tid] = map[bm + tid];
    __syncthreads();

    float acc[8][8];
    #pragma unroll
    for (int i=0;i<8;i++)
        #pragma unroll
        for (int j=0;j<8;j++) acc[i][j] = 0.f;

    int tx = tid & 15, ty = tid >> 4;

    for (int k0 = 0; k0 < Dn; k0 += 16){
        #pragma unroll
        for (int l=0;l<2;l++){
            int lin = tid + l*256;                 // 0..511
            int row = lin >> 2, kq = lin & 3;      // A: 128 rows x 4 float4
            const float4 v = *(const float4*)(X + (size_t)rows[row]*Dn + k0 + kq*4);
            As[kq*4+0][row] = v.x; As[kq*4+1][row] = v.y;
            As[kq*4+2][row] = v.z; As[kq*4+3][row] = v.w;
            int kk = lin >> 5, cq = lin & 31;      // B: 16 k-rows x 32 float4
            const float4 w = *(const float4*)(W + (size_t)(k0+kk)*Dn + bn + cq*4);
            *(float4*)&Bs[kk][cq*4] = w;
        }
        __syncthreads();
        #pragma unroll
        for (int kk=0; kk<16; kk++){
            float a[8], bb[8];
            *(float4*)&a[0]  = *(const float4*)&As[kk][ty*8];
            *(float4*)&a[4]  = *(const float4*)&As[kk][ty*8+4];
            *(float4*)&bb[0] = *(const float4*)&Bs[kk][tx*8];
            *(float4*)&bb[4] = *(const float4*)&Bs[kk][tx*8+4];
            #pragma unroll
            for (int i=0;i<8;i++)
                #pragma unroll
                for (int j=0;j<8;j++)
                    acc[i][j] = fmaf(a[i], bb[j], acc[i][j]);
        }
        __syncthreads();
    }
    #pragma unroll
    for (int i=0;i<8;i++){
        float* orow = O + (size_t)(bm + ty*8 + i)*Dn + bn + tx*8;
        *(float4*)orow     = make_float4(acc[i][0],acc[i][1],acc[i][2],acc[i][3]);
        *(float4*)(orow+4) = make_float4(acc[i][4],acc[i][5],acc[i][6],acc[i][7]);
    }
}

// one wave per dst row: emb = dinv_i^2*xw[i] + sum_e dinv[src]*dinv_i*xw[src] + bias
// out[b][omap[i]] += tanh(gate) * emb      (unique rows per launch -> non-atomic RMW)
__global__ __launch_bounds__(256) void k_agg(const int* __restrict__ csr,
                                             const int* __restrict__ offsets,
                                             const float* __restrict__ dinv,
                                             const float* __restrict__ xw,
                                             const float* __restrict__ be,
                                             const float* __restrict__ bn_,
                                             const int* __restrict__ e2t,
                                             const int* __restrict__ n2t,
                                             const float* __restrict__ ga,
                                             const float* __restrict__ gb,
                                             float* __restrict__ out,
                                             int g, int b0, int slot0){
    int zb = blockIdx.z;
    int b  = b0 + zb;
    int gi = g*4 + b;
    int wave = threadIdx.x >> 6, lane = threadIdx.x & 63;
    int i = blockIdx.x*4 + wave;                    // dst row
    const float* bias = g ? bn_ : be;
    const int*   omap = (g ? n2t : e2t) + b*NSUB;
    float gate = tanhf(g ? gb[0] : ga[0]);
    const float* xws = xw + (size_t)(slot0 + zb)*NSUB*Dn;

    int start = offsets[gi*NSUB + i];
    int end   = (i == NSUB-1) ? EG : offsets[gi*NSUB + i + 1];
    float di  = dinv[gi*NSUB + i];

    const float4* xr = (const float4*)(xws + (size_t)i*Dn);
    float s = di*di;
    float4 a0 = xr[lane], a1 = xr[64+lane], a2 = xr[128+lane];
    float4 acc0 = make_float4(s*a0.x, s*a0.y, s*a0.z, s*a0.w);
    float4 acc1 = make_float4(s*a1.x, s*a1.y, s*a1.z, s*a1.w);
    float4 acc2 = make_float4(s*a2.x, s*a2.y, s*a2.z, s*a2.w);

    for (int e = start; e < end; e++){
        int src = csr[(size_t)gi*EG + e];
        float w = dinv[gi*NSUB + src] * di;
        const float4* xs = (const float4*)(xws + (size_t)src*Dn);
        fma4(acc0, w, xs[lane]);
        fma4(acc1, w, xs[64+lane]);
        fma4(acc2, w, xs[128+lane]);
    }

    const float4* bi = (const float4*)bias;
    float4 b0v = bi[lane], b1v = bi[64+lane], b2v = bi[128+lane];

    int tok = omap[i];
    float4* o = (float4*)(out + ((size_t)b*Sn + tok)*Dn);
    float4 c0 = o[lane], c1 = o[64+lane], c2 = o[128+lane];
    o[lane]      = make_float4(c0.x + gate*(acc0.x+b0v.x), c0.y + gate*(acc0.y+b0v.y),
                               c0.z + gate*(acc0.z+b0v.z), c0.w + gate*(acc0.w+b0v.w));
    o[64+lane]   = make_float4(c1.x + gate*(acc1.x+b1v.x), c1.y + gate*(acc1.y+b1v.y),
                               c1.z + gate*(acc1.z+b1v.z), c1.w + gate*(acc1.w+b1v.w));
    o[128+lane]  = make_float4(c2.x + gate*(acc2.x+b2v.x), c2.y + gate*(acc2.y+b2v.y),
                               c2.z + gate*(acc2.z+b2v.z), c2.w + gate*(acc2.w+b2v.w));
}

extern "C" void kernel_launch(void* const* d_in, const int* in_sizes, int n_in,
                              void* d_out, int out_size, void* d_ws, size_t ws_size,
                              hipStream_t stream){
    const float* T   = (const float*)d_in[0];
    const int*   t2e = (const int*)d_in[1];
    const int*   e2t = (const int*)d_in[2];
    const int*   t2n = (const int*)d_in[3];
    const int*   n2t = (const int*)d_in[4];
    const int*   eie = (const int*)d_in[5];
    const int*   ein = (const int*)d_in[6];
    const float* We  = (const float*)d_in[7];
    const float* be  = (const float*)d_in[8];
    const float* Wn  = (const float*)d_in[9];
    const float* bnn = (const float*)d_in[10];
    const float* ga  = (const float*)d_in[11];
    const float* gb  = (const float*)d_in[12];
    float* out = (float*)d_out;

    char* ws = (char*)d_ws;
    int*   counts  = (int*)(ws + OFF_COUNTS);
    int*   offsets = (int*)(ws + OFF_OFFSETS);
    int*   pos     = (int*)(ws + OFF_POS);
    float* dinv    = (float*)(ws + OFF_DINV);
    int*   csr     = (int*)(ws + OFF_CSR);
    float* xw      = (float*)(ws + OFF_XW);

    size_t xw_slot = (size_t)NSUB*Dn*4;
    bool full = ws_size >= (size_t)OFF_XW + 8*xw_slot;

    k_zero<<<dim3((8*NSUB+255)/256), 256, 0, stream>>>(counts, 8*NSUB);
    int n4 = Bn*Sn*Dn/4;
    k_copy<<<dim3(2048), 256, 0, stream>>>((const float4*)T, (float4*)out, n4);
    k_count<<<dim3(32,1,8), 256, 0, stream>>>(eie, ein, counts);
    k_scan<<<dim3(8), 256, 0, stream>>>(counts, offsets, pos, dinv);
    k_fill<<<dim3(32,1,8), 256, 0, stream>>>(eie, ein, pos, csr);

    if (full){
        k_gemm<<<dim3(32,6,8), 256, 0, stream>>>(T, t2e, t2n, We, Wn, xw, 0);
        k_agg<<<dim3(1024,1,4), 256, 0, stream>>>(csr, offsets, dinv, xw, be, bnn,
                                                  e2t, n2t, ga, gb, out, 0, 0, 0);
        k_agg<<<dim3(1024,1,4), 256, 0, stream>>>(csr, offsets, dinv, xw, be, bnn,
                                                  e2t, n2t, ga, gb, out, 1, 0, 4);
    } else {
        for (int gi = 0; gi < 8; ++gi){
            k_gemm<<<dim3(32,6,1), 256, 0, stream>>>(T, t2e, t2n, We, Wn, xw, gi);
            k_agg<<<dim3(1024,1,1), 256, 0, stream>>>(csr, offsets, dinv, xw, be, bnn,
                                                      e2t, n2t, ga, gb, out, gi>>2, gi&3, 0);
        }
    }
}

// Round 2
// 504.349 us; speedup vs baseline: 1.6071x; 1.6071x over previous
//
#include <hip/hip_runtime.h>
#include <math.h>

#define Bn 4
#define Sn 8192
#define Dn 768
#define NSUB 4096
#define EG 32768

// ---- workspace layout (bytes) ----
#define OFF_COUNTS   0
#define OFF_OFFSETS  (8*NSUB*4)
#define OFF_POS      (2*8*NSUB*4)
#define OFF_DINV     (3*8*NSUB*4)
#define OFF_CSR      (4*8*NSUB*4)
#define OFF_WT       (OFF_CSR + 8*EG*4)            // 2 graphs x (hi,lo) x 768x768 ushort
#define WT_BYTES     (2*2*Dn*Dn*2)
#define OFF_XW       (OFF_WT + WT_BYTES)

typedef __attribute__((ext_vector_type(8))) short short8;
typedef __attribute__((ext_vector_type(4))) short short4v;
typedef __attribute__((ext_vector_type(4))) float f32x4;

__device__ __forceinline__ unsigned short bf16_rne(float v){
    unsigned u = __float_as_uint(v);
    return (unsigned short)((u + 0x7FFFu + ((u >> 16) & 1u)) >> 16);
}
__device__ __forceinline__ void split2(float v, unsigned short& h, unsigned short& l){
    h = bf16_rne(v);
    float hf = __uint_as_float(((unsigned)h) << 16);
    l = bf16_rne(v - hf);
}

__device__ __forceinline__ void fma4(float4& a, float w, const float4& v){
    a.x = fmaf(w, v.x, a.x); a.y = fmaf(w, v.y, a.y);
    a.z = fmaf(w, v.z, a.z); a.w = fmaf(w, v.w, a.w);
}

__global__ __launch_bounds__(256) void k_zero(int* __restrict__ p, int n){
    int i = blockIdx.x*256 + threadIdx.x;
    if (i < n) p[i] = 0;
}

__global__ __launch_bounds__(256) void k_copy(const float4* __restrict__ in,
                                              float4* __restrict__ out, int n4){
    int stride = gridDim.x*256;
    for (int i = blockIdx.x*256 + threadIdx.x; i < n4; i += stride) out[i] = in[i];
}

__global__ __launch_bounds__(256) void k_count(const int* __restrict__ eie,
                                               const int* __restrict__ ein,
                                               int* __restrict__ counts){
    int gi = blockIdx.z; int g = gi >> 2, b = gi & 3;
    const int* dst = (g ? ein : eie) + ((size_t)b*2 + 1)*EG;
    int* c = counts + gi*NSUB;
    for (int e = blockIdx.x*256 + threadIdx.x; e < EG; e += gridDim.x*256)
        atomicAdd(&c[dst[e]], 1);
}

__global__ __launch_bounds__(256) void k_scan(const int* __restrict__ counts,
                                              int* __restrict__ offsets,
                                              int* __restrict__ pos,
                                              float* __restrict__ dinv){
    int gi = blockIdx.x;
    int t  = threadIdx.x;
    __shared__ int part[256];
    const int* c = counts + gi*NSUB;
    int loc[16]; int s = 0;
    int base = t*16;
    #pragma unroll
    for (int j=0;j<16;j++){ loc[j] = s; s += c[base+j]; }
    part[t] = s;
    __syncthreads();
    for (int off=1; off<256; off<<=1){
        int v = 0;
        if (t >= off) v = part[t-off];
        __syncthreads();
        if (t >= off) part[t] += v;
        __syncthreads();
    }
    int prefix = (t==0) ? 0 : part[t-1];
    #pragma unroll
    for (int j=0;j<16;j++){
        int o = prefix + loc[j];
        offsets[gi*NSUB + base + j] = o;
        pos[gi*NSUB + base + j]     = o;
        dinv[gi*NSUB + base + j]    = 1.0f / sqrtf((float)(c[base+j] + 1));
    }
}

__global__ __launch_bounds__(256) void k_fill(const int* __restrict__ eie,
                                              const int* __restrict__ ein,
                                              int* __restrict__ pos,
                                              int* __restrict__ csr){
    int gi = blockIdx.z; int g = gi >> 2, b = gi & 3;
    const int* ei = (g ? ein : eie) + (size_t)b*2*EG;
    int* p  = pos + gi*NSUB;
    int* cs = csr + (size_t)gi*EG;
    for (int e = blockIdx.x*256 + threadIdx.x; e < EG; e += gridDim.x*256){
        int src = ei[e], d = ei[EG + e];
        int q = atomicAdd(&p[d], 1);
        cs[q] = src;
    }
}

// split W into WT_hi/WT_lo, transposed: WT[g][hilo][n][k] (ushort bf16 bits)
__global__ __launch_bounds__(256) void k_wsplit(const float* __restrict__ We,
                                                const float* __restrict__ Wn,
                                                unsigned short* __restrict__ WT){
    __shared__ float tile[32][33];
    int g = blockIdx.z;
    const float* W = g ? Wn : We;
    int k0 = blockIdx.x*32, n0 = blockIdx.y*32;
    int tx = threadIdx.x & 31, ty = threadIdx.x >> 5;   // 32 x 8
    for (int r = ty; r < 32; r += 8) tile[r][tx] = W[(size_t)(k0 + r)*Dn + n0 + tx];
    __syncthreads();
    unsigned short* hi = WT + (size_t)g*2*Dn*Dn;
    unsigned short* lo = hi + (size_t)Dn*Dn;
    for (int r = ty; r < 32; r += 8){
        float v = tile[tx][r];                 // = W[k0+tx][n0+r]
        unsigned short h, l;
        split2(v, h, l);
        hi[(size_t)(n0 + r)*Dn + k0 + tx] = h;
        lo[(size_t)(n0 + r)*Dn + k0 + tx] = l;
    }
}

// split-bf16 3-pass MFMA GEMM: xw[slot][i][:] = T[b][map[i]][:] @ W
// 128x128 tile, BK=32, 4 waves x (64x64), 16x16x32 bf16 MFMA.
__global__ __launch_bounds__(256) void k_gemm(const float* __restrict__ T,
                                              const int* __restrict__ t2e,
                                              const int* __restrict__ t2n,
                                              const unsigned short* __restrict__ WT,
                                              float* __restrict__ xw, int gi0){
    int z = blockIdx.z; int gi = gi0 + z;
    int g = gi >> 2, b = gi & 3;
    const int*   map = (g ? t2n : t2e) + b*NSUB;
    const float* X   = T + (size_t)b*Sn*Dn;
    const unsigned short* WTh = WT + (size_t)g*2*Dn*Dn;
    const unsigned short* WTl = WTh + (size_t)Dn*Dn;
    float* O = xw + (size_t)z*NSUB*Dn;

    __shared__ unsigned short AsH[128*32], AsL[128*32], BsH[128*32], BsL[128*32];
    __shared__ int rows[128];

    int bm = blockIdx.x*128, bn = blockIdx.y*128;
    int tid = threadIdx.x;
    if (tid < 128) rows[tid] = map[bm + tid];
    __syncthreads();

    int lane = tid & 63, wid = tid >> 6;
    int wm = (wid >> 1)*64, wn = (wid & 1)*64;

    // precomputed staging addresses (constant across K-steps)
    const float* aptr[4]; int aidx[4];
    #pragma unroll
    for (int l=0;l<4;l++){
        int lin = tid + l*256;                 // 0..1023 : row 0..127, f 0..7
        int row = lin >> 3, f = lin & 7;
        aptr[l] = X + (size_t)rows[row]*Dn + f*4;
        int c = f >> 1, cp = c ^ ((row >> 1) & 3);
        aidx[l] = row*32 + cp*8 + (f&1)*4;
    }
    int bsrc[2], bdst[2];
    #pragma unroll
    for (int l=0;l<2;l++){
        int ci = tid + l*256;                  // 0..511 : n 0..127, c 0..3
        int n = ci >> 2, c = ci & 3;
        int cp = c ^ ((n >> 1) & 3);
        bsrc[l] = (bn + n)*Dn + c*8;
        bdst[l] = n*32 + cp*8;
    }
    // fragment read offsets
    int aoff[4], boff[4];
    int kc = lane >> 4;
    #pragma unroll
    for (int mt=0; mt<4; mt++){
        int r = wm + mt*16 + (lane & 15);
        aoff[mt] = r*32 + (kc ^ ((r >> 1) & 3))*8;
    }
    #pragma unroll
    for (int nt=0; nt<4; nt++){
        int cn = wn + nt*16 + (lane & 15);
        boff[nt] = cn*32 + (kc ^ ((cn >> 1) & 3))*8;
    }

    f32x4 acc[4][4];
    #pragma unroll
    for (int i=0;i<4;i++)
        #pragma unroll
        for (int j=0;j<4;j++)
            acc[i][j] = f32x4{0.f,0.f,0.f,0.f};

    for (int k0 = 0; k0 < Dn; k0 += 32){
        // stage A (fp32 -> hi/lo bf16)
        #pragma unroll
        for (int l=0;l<4;l++){
            float4 v = *(const float4*)(aptr[l] + k0);
            short4v h, lo;
            unsigned short hh, ll;
            split2(v.x, hh, ll); h.x = (short)hh; lo.x = (short)ll;
            split2(v.y, hh, ll); h.y = (short)hh; lo.y = (short)ll;
            split2(v.z, hh, ll); h.z = (short)hh; lo.z = (short)ll;
            split2(v.w, hh, ll); h.w = (short)hh; lo.w = (short)ll;
            *(short4v*)&AsH[aidx[l]] = h;
            *(short4v*)&AsL[aidx[l]] = lo;
        }
        // stage B (pre-split bf16, straight copy)
        #pragma unroll
        for (int l=0;l<2;l++){
            *(short8*)&BsH[bdst[l]] = *(const short8*)&WTh[bsrc[l] + k0];
            *(short8*)&BsL[bdst[l]] = *(const short8*)&WTl[bsrc[l] + k0];
        }
        __syncthreads();

        short8 ah[4], al[4];
        #pragma unroll
        for (int mt=0; mt<4; mt++){
            ah[mt] = *(const short8*)&AsH[aoff[mt]];
            al[mt] = *(const short8*)&AsL[aoff[mt]];
        }
        #pragma unroll
        for (int nt=0; nt<4; nt++){
            short8 bh = *(const short8*)&BsH[boff[nt]];
            short8 bl = *(const short8*)&BsL[boff[nt]];
            #pragma unroll
            for (int mt=0; mt<4; mt++){
                acc[mt][nt] = __builtin_amdgcn_mfma_f32_16x16x32_bf16(ah[mt], bh, acc[mt][nt], 0, 0, 0);
                acc[mt][nt] = __builtin_amdgcn_mfma_f32_16x16x32_bf16(al[mt], bh, acc[mt][nt], 0, 0, 0);
                acc[mt][nt] = __builtin_amdgcn_mfma_f32_16x16x32_bf16(ah[mt], bl, acc[mt][nt], 0, 0, 0);
            }
        }
        __syncthreads();
    }

    // epilogue: C[row][col], row=(lane>>4)*4+j, col=lane&15 per 16x16 tile
    int r0 = (lane >> 4)*4, cc = lane & 15;
    #pragma unroll
    for (int mt=0; mt<4; mt++){
        #pragma unroll
        for (int j=0; j<4; j++){
            int row = bm + wm + mt*16 + r0 + j;
            float* orow = O + (size_t)row*Dn + bn + wn + cc;
            #pragma unroll
            for (int nt=0; nt<4; nt++) orow[nt*16] = acc[mt][nt][j];
        }
    }
}

__global__ __launch_bounds__(256) void k_agg(const int* __restrict__ csr,
                                             const int* __restrict__ offsets,
                                             const float* __restrict__ dinv,
                                             const float* __restrict__ xw,
                                             const float* __restrict__ be,
                                             const float* __restrict__ bn_,
                                             const int* __restrict__ e2t,
                                             const int* __restrict__ n2t,
                                             const float* __restrict__ ga,
                                             const float* __restrict__ gb,
                                             float* __restrict__ out,
                                             int g, int b0, int slot0){
    int zb = blockIdx.z;
    int b  = b0 + zb;
    int gi = g*4 + b;
    int wave = threadIdx.x >> 6, lane = threadIdx.x & 63;
    int i = blockIdx.x*4 + wave;
    const float* bias = g ? bn_ : be;
    const int*   omap = (g ? n2t : e2t) + b*NSUB;
    float gate = tanhf(g ? gb[0] : ga[0]);
    const float* xws = xw + (size_t)(slot0 + zb)*NSUB*Dn;

    int start = offsets[gi*NSUB + i];
    int end   = (i == NSUB-1) ? EG : offsets[gi*NSUB + i + 1];
    float di  = dinv[gi*NSUB + i];

    const float4* xr = (const float4*)(xws + (size_t)i*Dn);
    float s = di*di;
    float4 a0 = xr[lane], a1 = xr[64+lane], a2 = xr[128+lane];
    float4 acc0 = make_float4(s*a0.x, s*a0.y, s*a0.z, s*a0.w);
    float4 acc1 = make_float4(s*a1.x, s*a1.y, s*a1.z, s*a1.w);
    float4 acc2 = make_float4(s*a2.x, s*a2.y, s*a2.z, s*a2.w);

    for (int e = start; e < end; e++){
        int src = csr[(size_t)gi*EG + e];
        float w = dinv[gi*NSUB + src] * di;
        const float4* xs = (const float4*)(xws + (size_t)src*Dn);
        fma4(acc0, w, xs[lane]);
        fma4(acc1, w, xs[64+lane]);
        fma4(acc2, w, xs[128+lane]);
    }

    const float4* bi = (const float4*)bias;
    float4 b0v = bi[lane], b1v = bi[64+lane], b2v = bi[128+lane];

    int tok = omap[i];
    float4* o = (float4*)(out + ((size_t)b*Sn + tok)*Dn);
    float4 c0 = o[lane], c1 = o[64+lane], c2 = o[128+lane];
    o[lane]      = make_float4(c0.x + gate*(acc0.x+b0v.x), c0.y + gate*(acc0.y+b0v.y),
                               c0.z + gate*(acc0.z+b0v.z), c0.w + gate*(acc0.w+b0v.w));
    o[64+lane]   = make_float4(c1.x + gate*(acc1.x+b1v.x), c1.y + gate*(acc1.y+b1v.y),
                               c1.z + gate*(acc1.z+b1v.z), c1.w + gate*(acc1.w+b1v.w));
    o[128+lane]  = make_float4(c2.x + gate*(acc2.x+b2v.x), c2.y + gate*(acc2.y+b2v.y),
                               c2.z + gate*(acc2.z+b2v.z), c2.w + gate*(acc2.w+b2v.w));
}

extern "C" void kernel_launch(void* const* d_in, const int* in_sizes, int n_in,
                              void* d_out, int out_size, void* d_ws, size_t ws_size,
                              hipStream_t stream){
    const float* T   = (const float*)d_in[0];
    const int*   t2e = (const int*)d_in[1];
    const int*   e2t = (const int*)d_in[2];
    const int*   t2n = (const int*)d_in[3];
    const int*   n2t = (const int*)d_in[4];
    const int*   eie = (const int*)d_in[5];
    const int*   ein = (const int*)d_in[6];
    const float* We  = (const float*)d_in[7];
    const float* be  = (const float*)d_in[8];
    const float* Wn  = (const float*)d_in[9];
    const float* bnn = (const float*)d_in[10];
    const float* ga  = (const float*)d_in[11];
    const float* gb  = (const float*)d_in[12];
    float* out = (float*)d_out;

    char* ws = (char*)d_ws;
    int*   counts  = (int*)(ws + OFF_COUNTS);
    int*   offsets = (int*)(ws + OFF_OFFSETS);
    int*   pos     = (int*)(ws + OFF_POS);
    float* dinv    = (float*)(ws + OFF_DINV);
    int*   csr     = (int*)(ws + OFF_CSR);
    unsigned short* WT = (unsigned short*)(ws + OFF_WT);
    float* xw      = (float*)(ws + OFF_XW);

    size_t xw_slot = (size_t)NSUB*Dn*4;
    bool full = ws_size >= (size_t)OFF_XW + 8*xw_slot;

    k_zero<<<dim3((8*NSUB+255)/256), 256, 0, stream>>>(counts, 8*NSUB);
    int n4 = Bn*Sn*Dn/4;
    k_copy<<<dim3(2048), 256, 0, stream>>>((const float4*)T, (float4*)out, n4);
    k_count<<<dim3(32,1,8), 256, 0, stream>>>(eie, ein, counts);
    k_wsplit<<<dim3(24,24,2), 256, 0, stream>>>(We, Wn, WT);
    k_scan<<<dim3(8), 256, 0, stream>>>(counts, offsets, pos, dinv);
    k_fill<<<dim3(32,1,8), 256, 0, stream>>>(eie, ein, pos, csr);

    if (full){
        k_gemm<<<dim3(32,6,8), 256, 0, stream>>>(T, t2e, t2n, WT, xw, 0);
        k_agg<<<dim3(1024,1,4), 256, 0, stream>>>(csr, offsets, dinv, xw, be, bnn,
                                                  e2t, n2t, ga, gb, out, 0, 0, 0);
        k_agg<<<dim3(1024,1,4), 256, 0, stream>>>(csr, offsets, dinv, xw, be, bnn,
                                                  e2t, n2t, ga, gb, out, 1, 0, 4);
    } else {
        for (int gi = 0; gi < 8; ++gi){
            k_gemm<<<dim3(32,6,1), 256, 0, stream>>>(T, t2e, t2n, WT, xw, gi);
            k_agg<<<dim3(1024,1,1), 256, 0, stream>>>(csr, offsets, dinv, xw, be, bnn,
                                                      e2t, n2t, ga, gb, out, gi>>2, gi&3, 0);
        }
    }
}

// Round 3
// 497.828 us; speedup vs baseline: 1.6281x; 1.0131x over previous
//
#include <hip/hip_runtime.h>
#include <math.h>

#define Bn 4
#define Sn 8192
#define Dn 768
#define NSUB 4096
#define EG 32768

// ---- workspace layout (bytes) ----
#define OFF_COUNTS   0
#define OFF_OFFSETS  131072
#define OFF_POS      262144
#define OFF_DINV     393216
#define OFF_CSR      524288
#define OFF_INV      1572864
#define OFF_WT       1835008
#define OFF_XW       6553600
#define OFF_EMB      107216896
#define WS_END       207880192

typedef __attribute__((ext_vector_type(8))) short short8;
typedef __attribute__((ext_vector_type(4))) short short4v;
typedef __attribute__((ext_vector_type(4))) float f32x4;

__device__ __forceinline__ unsigned short bf16_rne(float v){
    unsigned u = __float_as_uint(v);
    return (unsigned short)((u + 0x7FFFu + ((u >> 16) & 1u)) >> 16);
}
__device__ __forceinline__ void split2(float v, unsigned short& h, unsigned short& l){
    h = bf16_rne(v);
    float hf = __uint_as_float(((unsigned)h) << 16);
    l = bf16_rne(v - hf);
}

__device__ __forceinline__ void fma4(float4& a, float w, const float4& v){
    a.x = fmaf(w, v.x, a.x); a.y = fmaf(w, v.y, a.y);
    a.z = fmaf(w, v.z, a.z); a.w = fmaf(w, v.w, a.w);
}

__global__ __launch_bounds__(256) void k_zero(int* __restrict__ p, int v, int n){
    int i = blockIdx.x*256 + threadIdx.x;
    if (i < n) p[i] = v;
}

__global__ __launch_bounds__(256) void k_copy(const float4* __restrict__ in,
                                              float4* __restrict__ out, int n4){
    int stride = gridDim.x*256;
    for (int i = blockIdx.x*256 + threadIdx.x; i < n4; i += stride) out[i] = in[i];
}

__global__ __launch_bounds__(256) void k_count(const int* __restrict__ eie,
                                               const int* __restrict__ ein,
                                               int* __restrict__ counts){
    int gi = blockIdx.z; int g = gi >> 2, b = gi & 3;
    const int* dst = (g ? ein : eie) + ((size_t)b*2 + 1)*EG;
    int* c = counts + gi*NSUB;
    for (int e = blockIdx.x*256 + threadIdx.x; e < EG; e += gridDim.x*256)
        atomicAdd(&c[dst[e]], 1);
}

__global__ __launch_bounds__(256) void k_scan(const int* __restrict__ counts,
                                              int* __restrict__ offsets,
                                              int* __restrict__ pos,
                                              float* __restrict__ dinv){
    int gi = blockIdx.x;
    int t  = threadIdx.x;
    __shared__ int part[256];
    const int* c = counts + gi*NSUB;
    int loc[16]; int s = 0;
    int base = t*16;
    #pragma unroll
    for (int j=0;j<16;j++){ loc[j] = s; s += c[base+j]; }
    part[t] = s;
    __syncthreads();
    for (int off=1; off<256; off<<=1){
        int v = 0;
        if (t >= off) v = part[t-off];
        __syncthreads();
        if (t >= off) part[t] += v;
        __syncthreads();
    }
    int prefix = (t==0) ? 0 : part[t-1];
    #pragma unroll
    for (int j=0;j<16;j++){
        int o = prefix + loc[j];
        offsets[gi*NSUB + base + j] = o;
        pos[gi*NSUB + base + j]     = o;
        dinv[gi*NSUB + base + j]    = 1.0f / sqrtf((float)(c[base+j] + 1));
    }
}

__global__ __launch_bounds__(256) void k_fill(const int* __restrict__ eie,
                                              const int* __restrict__ ein,
                                              int* __restrict__ pos,
                                              int* __restrict__ csr){
    int gi = blockIdx.z; int g = gi >> 2, b = gi & 3;
    const int* ei = (g ? ein : eie) + (size_t)b*2*EG;
    int* p  = pos + gi*NSUB;
    int* cs = csr + (size_t)gi*EG;
    for (int e = blockIdx.x*256 + threadIdx.x; e < EG; e += gridDim.x*256){
        int src = ei[e], d = ei[EG + e];
        int q = atomicAdd(&p[d], 1);
        cs[q] = src;
    }
}

// inverse scatter maps: inv[gi][tok] = row i (or -1)
__global__ __launch_bounds__(256) void k_inv(const int* __restrict__ e2t,
                                             const int* __restrict__ n2t,
                                             int* __restrict__ inv){
    int gi = blockIdx.z; int g = gi >> 2, b = gi & 3;
    const int* omap = (g ? n2t : e2t) + b*NSUB;
    int i = blockIdx.x*256 + threadIdx.x;
    if (i < NSUB) inv[(size_t)gi*Sn + omap[i]] = i;
}

__global__ __launch_bounds__(256) void k_wsplit(const float* __restrict__ We,
                                                const float* __restrict__ Wn,
                                                unsigned short* __restrict__ WT){
    __shared__ float tile[32][33];
    int g = blockIdx.z;
    const float* W = g ? Wn : We;
    int k0 = blockIdx.x*32, n0 = blockIdx.y*32;
    int tx = threadIdx.x & 31, ty = threadIdx.x >> 5;
    for (int r = ty; r < 32; r += 8) tile[r][tx] = W[(size_t)(k0 + r)*Dn + n0 + tx];
    __syncthreads();
    unsigned short* hi = WT + (size_t)g*2*Dn*Dn;
    unsigned short* lo = hi + (size_t)Dn*Dn;
    for (int r = ty; r < 32; r += 8){
        float v = tile[tx][r];
        unsigned short h, l;
        split2(v, h, l);
        hi[(size_t)(n0 + r)*Dn + k0 + tx] = h;
        lo[(size_t)(n0 + r)*Dn + k0 + tx] = l;
    }
}

// split-bf16 3-pass MFMA GEMM (unchanged from R2; 763 TF effective)
__global__ __launch_bounds__(256) void k_gemm(const float* __restrict__ T,
                                              const int* __restrict__ t2e,
                                              const int* __restrict__ t2n,
                                              const unsigned short* __restrict__ WT,
                                              float* __restrict__ xw, int gi0){
    int z = blockIdx.z; int gi = gi0 + z;
    int g = gi >> 2, b = gi & 3;
    const int*   map = (g ? t2n : t2e) + b*NSUB;
    const float* X   = T + (size_t)b*Sn*Dn;
    const unsigned short* WTh = WT + (size_t)g*2*Dn*Dn;
    const unsigned short* WTl = WTh + (size_t)Dn*Dn;
    float* O = xw + (size_t)z*NSUB*Dn;

    __shared__ unsigned short AsH[128*32], AsL[128*32], BsH[128*32], BsL[128*32];
    __shared__ int rows[128];

    int bm = blockIdx.x*128, bn = blockIdx.y*128;
    int tid = threadIdx.x;
    if (tid < 128) rows[tid] = map[bm + tid];
    __syncthreads();

    int lane = tid & 63, wid = tid >> 6;
    int wm = (wid >> 1)*64, wn = (wid & 1)*64;

    const float* aptr[4]; int aidx[4];
    #pragma unroll
    for (int l=0;l<4;l++){
        int lin = tid + l*256;
        int row = lin >> 3, f = lin & 7;
        aptr[l] = X + (size_t)rows[row]*Dn + f*4;
        int c = f >> 1, cp = c ^ ((row >> 1) & 3);
        aidx[l] = row*32 + cp*8 + (f&1)*4;
    }
    int bsrc[2], bdst[2];
    #pragma unroll
    for (int l=0;l<2;l++){
        int ci = tid + l*256;
        int n = ci >> 2, c = ci & 3;
        int cp = c ^ ((n >> 1) & 3);
        bsrc[l] = (bn + n)*Dn + c*8;
        bdst[l] = n*32 + cp*8;
    }
    int aoff[4], boff[4];
    int kc = lane >> 4;
    #pragma unroll
    for (int mt=0; mt<4; mt++){
        int r = wm + mt*16 + (lane & 15);
        aoff[mt] = r*32 + (kc ^ ((r >> 1) & 3))*8;
    }
    #pragma unroll
    for (int nt=0; nt<4; nt++){
        int cn = wn + nt*16 + (lane & 15);
        boff[nt] = cn*32 + (kc ^ ((cn >> 1) & 3))*8;
    }

    f32x4 acc[4][4];
    #pragma unroll
    for (int i=0;i<4;i++)
        #pragma unroll
        for (int j=0;j<4;j++)
            acc[i][j] = f32x4{0.f,0.f,0.f,0.f};

    for (int k0 = 0; k0 < Dn; k0 += 32){
        #pragma unroll
        for (int l=0;l<4;l++){
            float4 v = *(const float4*)(aptr[l] + k0);
            short4v h, lo;
            unsigned short hh, ll;
            split2(v.x, hh, ll); h.x = (short)hh; lo.x = (short)ll;
            split2(v.y, hh, ll); h.y = (short)hh; lo.y = (short)ll;
            split2(v.z, hh, ll); h.z = (short)hh; lo.z = (short)ll;
            split2(v.w, hh, ll); h.w = (short)hh; lo.w = (short)ll;
            *(short4v*)&AsH[aidx[l]] = h;
            *(short4v*)&AsL[aidx[l]] = lo;
        }
        #pragma unroll
        for (int l=0;l<2;l++){
            *(short8*)&BsH[bdst[l]] = *(const short8*)&WTh[bsrc[l] + k0];
            *(short8*)&BsL[bdst[l]] = *(const short8*)&WTl[bsrc[l] + k0];
        }
        __syncthreads();

        short8 ah[4], al[4];
        #pragma unroll
        for (int mt=0; mt<4; mt++){
            ah[mt] = *(const short8*)&AsH[aoff[mt]];
            al[mt] = *(const short8*)&AsL[aoff[mt]];
        }
        #pragma unroll
        for (int nt=0; nt<4; nt++){
            short8 bh = *(const short8*)&BsH[boff[nt]];
            short8 bl = *(const short8*)&BsL[boff[nt]];
            #pragma unroll
            for (int mt=0; mt<4; mt++){
                acc[mt][nt] = __builtin_amdgcn_mfma_f32_16x16x32_bf16(ah[mt], bh, acc[mt][nt], 0, 0, 0);
                acc[mt][nt] = __builtin_amdgcn_mfma_f32_16x16x32_bf16(al[mt], bh, acc[mt][nt], 0, 0, 0);
                acc[mt][nt] = __builtin_amdgcn_mfma_f32_16x16x32_bf16(ah[mt], bl, acc[mt][nt], 0, 0, 0);
            }
        }
        __syncthreads();
    }

    int r0 = (lane >> 4)*4, cc = lane & 15;
    #pragma unroll
    for (int mt=0; mt<4; mt++){
        #pragma unroll
        for (int j=0; j<4; j++){
            int row = bm + wm + mt*16 + r0 + j;
            float* orow = O + (size_t)row*Dn + bn + wn + cc;
            #pragma unroll
            for (int nt=0; nt<4; nt++) orow[nt*16] = acc[mt][nt][j];
        }
    }
}

// MODE 0: RMW into out[b][omap[i]] (legacy tier). MODE 1: write emb[gi][i].
// acc = di*xw_i + sum dinv[src]*xw[src]; result = gate*(di*acc + bias).
// 4-deep software-pipelined edge loop for memory-level parallelism.
template<int MODE>
__global__ __launch_bounds__(256) void k_agg(const int* __restrict__ csr,
                                             const int* __restrict__ offsets,
                                             const float* __restrict__ dinv,
                                             const float* __restrict__ xw,
                                             const float* __restrict__ be,
                                             const float* __restrict__ bn_,
                                             const int* __restrict__ e2t,
                                             const int* __restrict__ n2t,
                                             const float* __restrict__ ga,
                                             const float* __restrict__ gb,
                                             float* __restrict__ out,
                                             float* __restrict__ emb,
                                             int g0, int b0, int slot0){
    int zb = blockIdx.z;
    int gi, g, b, slot;
    if (MODE == 1){ gi = zb; g = gi >> 2; b = gi & 3; slot = zb; }
    else { g = g0; b = b0 + zb; gi = g*4 + b; slot = slot0 + zb; }
    int wave = threadIdx.x >> 6, lane = threadIdx.x & 63;
    int i = blockIdx.x*4 + wave;
    const float* bias = g ? bn_ : be;
    float gate = tanhf(g ? gb[0] : ga[0]);
    const float* xws = xw + (size_t)slot*NSUB*Dn;
    const float* dv  = dinv + gi*NSUB;
    const int*   cs  = csr + (size_t)gi*EG;

    int start = offsets[gi*NSUB + i];
    int end   = (i == NSUB-1) ? EG : offsets[gi*NSUB + i + 1];
    float di  = dv[i];

    const float4* xr = (const float4*)(xws + (size_t)i*Dn);
    float4 a0 = xr[lane], a1 = xr[64+lane], a2 = xr[128+lane];
    float4 acc0 = make_float4(di*a0.x, di*a0.y, di*a0.z, di*a0.w);
    float4 acc1 = make_float4(di*a1.x, di*a1.y, di*a1.z, di*a1.w);
    float4 acc2 = make_float4(di*a2.x, di*a2.y, di*a2.z, di*a2.w);

    int e = start;
    for (; e + 4 <= end; e += 4){
        int s0 = cs[e], s1 = cs[e+1], s2 = cs[e+2], s3 = cs[e+3];
        float w0 = dv[s0], w1 = dv[s1], w2 = dv[s2], w3 = dv[s3];
        const float4* p0 = (const float4*)(xws + (size_t)s0*Dn);
        const float4* p1 = (const float4*)(xws + (size_t)s1*Dn);
        const float4* p2 = (const float4*)(xws + (size_t)s2*Dn);
        const float4* p3 = (const float4*)(xws + (size_t)s3*Dn);
        float4 r00 = p0[lane], r01 = p0[64+lane], r02 = p0[128+lane];
        float4 r10 = p1[lane], r11 = p1[64+lane], r12 = p1[128+lane];
        float4 r20 = p2[lane], r21 = p2[64+lane], r22 = p2[128+lane];
        float4 r30 = p3[lane], r31 = p3[64+lane], r32 = p3[128+lane];
        fma4(acc0, w0, r00); fma4(acc1, w0, r01); fma4(acc2, w0, r02);
        fma4(acc0, w1, r10); fma4(acc1, w1, r11); fma4(acc2, w1, r12);
        fma4(acc0, w2, r20); fma4(acc1, w2, r21); fma4(acc2, w2, r22);
        fma4(acc0, w3, r30); fma4(acc1, w3, r31); fma4(acc2, w3, r32);
    }
    for (; e < end; e++){
        int src = cs[e];
        float w = dv[src];
        const float4* xs = (const float4*)(xws + (size_t)src*Dn);
        fma4(acc0, w, xs[lane]);
        fma4(acc1, w, xs[64+lane]);
        fma4(acc2, w, xs[128+lane]);
    }

    const float4* bi = (const float4*)bias;
    float4 b0v = bi[lane], b1v = bi[64+lane], b2v = bi[128+lane];

    if (MODE == 1){
        float4* er = (float4*)(emb + ((size_t)gi*NSUB + i)*Dn);
        er[lane]     = make_float4(gate*(di*acc0.x+b0v.x), gate*(di*acc0.y+b0v.y),
                                   gate*(di*acc0.z+b0v.z), gate*(di*acc0.w+b0v.w));
        er[64+lane]  = make_float4(gate*(di*acc1.x+b1v.x), gate*(di*acc1.y+b1v.y),
                                   gate*(di*acc1.z+b1v.z), gate*(di*acc1.w+b1v.w));
        er[128+lane] = make_float4(gate*(di*acc2.x+b2v.x), gate*(di*acc2.y+b2v.y),
                                   gate*(di*acc2.z+b2v.z), gate*(di*acc2.w+b2v.w));
    } else {
        const int* omap = (g ? n2t : e2t) + b*NSUB;
        int tok = omap[i];
        float4* o = (float4*)(out + ((size_t)b*Sn + tok)*Dn);
        float4 c0 = o[lane], c1 = o[64+lane], c2 = o[128+lane];
        o[lane]     = make_float4(c0.x + gate*(di*acc0.x+b0v.x), c0.y + gate*(di*acc0.y+b0v.y),
                                  c0.z + gate*(di*acc0.z+b0v.z), c0.w + gate*(di*acc0.w+b0v.w));
        o[64+lane]  = make_float4(c1.x + gate*(di*acc1.x+b1v.x), c1.y + gate*(di*acc1.y+b1v.y),
                                  c1.z + gate*(di*acc1.z+b1v.z), c1.w + gate*(di*acc1.w+b1v.w));
        o[128+lane] = make_float4(c2.x + gate*(di*acc2.x+b2v.x), c2.y + gate*(di*acc2.y+b2v.y),
                                  c2.z + gate*(di*acc2.z+b2v.z), c2.w + gate*(di*acc2.w+b2v.w));
    }
}

// out[b][tok] = T[b][tok] + emb_e[inv_e] + emb_n[inv_n]   (emb pre-gated+biased)
__global__ __launch_bounds__(256) void k_fuse(const float* __restrict__ T,
                                              const int* __restrict__ inv,
                                              const float* __restrict__ emb,
                                              float* __restrict__ out){
    int wave = threadIdx.x >> 6, lane = threadIdx.x & 63;
    int row = blockIdx.x*4 + wave;               // 0..Bn*Sn-1
    int b = row >> 13, tok = row & (Sn-1);

    const float4* tr = (const float4*)(T + (size_t)row*Dn);
    float4 t0 = tr[lane], t1 = tr[64+lane], t2 = tr[128+lane];

    int ie = inv[(size_t)b*Sn + tok];            // gi = 0*4+b
    int in_ = inv[(size_t)(4+b)*Sn + tok];       // gi = 4+b
    if (ie >= 0){
        const float4* er = (const float4*)(emb + ((size_t)b*NSUB + ie)*Dn);
        float4 e0 = er[lane], e1 = er[64+lane], e2 = er[128+lane];
        t0.x += e0.x; t0.y += e0.y; t0.z += e0.z; t0.w += e0.w;
        t1.x += e1.x; t1.y += e1.y; t1.z += e1.z; t1.w += e1.w;
        t2.x += e2.x; t2.y += e2.y; t2.z += e2.z; t2.w += e2.w;
    }
    if (in_ >= 0){
        const float4* er = (const float4*)(emb + ((size_t)(4+b)*NSUB + in_)*Dn);
        float4 e0 = er[lane], e1 = er[64+lane], e2 = er[128+lane];
        t0.x += e0.x; t0.y += e0.y; t0.z += e0.z; t0.w += e0.w;
        t1.x += e1.x; t1.y += e1.y; t1.z += e1.z; t1.w += e1.w;
        t2.x += e2.x; t2.y += e2.y; t2.z += e2.z; t2.w += e2.w;
    }
    float4* o = (float4*)(out + (size_t)row*Dn);
    o[lane] = t0; o[64+lane] = t1; o[128+lane] = t2;
}

extern "C" void kernel_launch(void* const* d_in, const int* in_sizes, int n_in,
                              void* d_out, int out_size, void* d_ws, size_t ws_size,
                              hipStream_t stream){
    const float* T   = (const float*)d_in[0];
    const int*   t2e = (const int*)d_in[1];
    const int*   e2t = (const int*)d_in[2];
    const int*   t2n = (const int*)d_in[3];
    const int*   n2t = (const int*)d_in[4];
    const int*   eie = (const int*)d_in[5];
    const int*   ein = (const int*)d_in[6];
    const float* We  = (const float*)d_in[7];
    const float* be  = (const float*)d_in[8];
    const float* Wn  = (const float*)d_in[9];
    const float* bnn = (const float*)d_in[10];
    const float* ga  = (const float*)d_in[11];
    const float* gb  = (const float*)d_in[12];
    float* out = (float*)d_out;

    char* ws = (char*)d_ws;
    int*   counts  = (int*)(ws + OFF_COUNTS);
    int*   offsets = (int*)(ws + OFF_OFFSETS);
    int*   pos     = (int*)(ws + OFF_POS);
    float* dinv    = (float*)(ws + OFF_DINV);
    int*   csr     = (int*)(ws + OFF_CSR);
    int*   inv     = (int*)(ws + OFF_INV);
    unsigned short* WT = (unsigned short*)(ws + OFF_WT);
    float* xw      = (float*)(ws + OFF_XW);
    float* emb     = (float*)(ws + OFF_EMB);

    size_t xw_slot = (size_t)NSUB*Dn*4;
    bool tier2 = ws_size >= (size_t)WS_END;
    bool tier1 = ws_size >= (size_t)OFF_XW + 8*xw_slot;

    k_zero<<<dim3((8*NSUB+255)/256), 256, 0, stream>>>(counts, 0, 8*NSUB);
    k_count<<<dim3(32,1,8), 256, 0, stream>>>(eie, ein, counts);
    k_wsplit<<<dim3(24,24,2), 256, 0, stream>>>(We, Wn, WT);
    k_scan<<<dim3(8), 256, 0, stream>>>(counts, offsets, pos, dinv);
    k_fill<<<dim3(32,1,8), 256, 0, stream>>>(eie, ein, pos, csr);

    if (tier2){
        k_zero<<<dim3((8*Sn+255)/256), 256, 0, stream>>>(inv, -1, 8*Sn);
        k_inv<<<dim3(16,1,8), 256, 0, stream>>>(e2t, n2t, inv);
        k_gemm<<<dim3(32,6,8), 256, 0, stream>>>(T, t2e, t2n, WT, xw, 0);
        k_agg<1><<<dim3(1024,1,8), 256, 0, stream>>>(csr, offsets, dinv, xw, be, bnn,
                                                     e2t, n2t, ga, gb, out, emb, 0, 0, 0);
        k_fuse<<<dim3(Bn*Sn/4), 256, 0, stream>>>(T, inv, emb, out);
    } else if (tier1){
        int n4 = Bn*Sn*Dn/4;
        k_copy<<<dim3(2048), 256, 0, stream>>>((const float4*)T, (float4*)out, n4);
        k_gemm<<<dim3(32,6,8), 256, 0, stream>>>(T, t2e, t2n, WT, xw, 0);
        k_agg<0><<<dim3(1024,1,4), 256, 0, stream>>>(csr, offsets, dinv, xw, be, bnn,
                                                     e2t, n2t, ga, gb, out, nullptr, 0, 0, 0);
        k_agg<0><<<dim3(1024,1,4), 256, 0, stream>>>(csr, offsets, dinv, xw, be, bnn,
                                                     e2t, n2t, ga, gb, out, nullptr, 1, 0, 4);
    } else {
        int n4 = Bn*Sn*Dn/4;
        k_copy<<<dim3(2048), 256, 0, stream>>>((const float4*)T, (float4*)out, n4);
        for (int gi = 0; gi < 8; ++gi){
            k_gemm<<<dim3(32,6,1), 256, 0, stream>>>(T, t2e, t2n, WT, xw, gi);
            k_agg<0><<<dim3(1024,1,1), 256, 0, stream>>>(csr, offsets, dinv, xw, be, bnn,
                                                         e2t, n2t, ga, gb, out, nullptr, gi>>2, gi&3, 0);
        }
    }
}

// Round 5
// 494.943 us; speedup vs baseline: 1.6376x; 1.0058x over previous
//
#include <hip/hip_runtime.h>
#include <math.h>

#define Bn 4
#define Sn 8192
#define Dn 768
#define NSUB 4096
#define EG 32768

// ---- workspace layout (bytes) ----
#define OFF_COUNTS   0
#define OFF_OFFSETS  131072
#define OFF_POS      262144
#define OFF_DINV     393216
#define OFF_CSR      524288
#define OFF_INV      1572864
#define OFF_WT       1835008
#define OFF_XW       6553600
#define OFF_EMB      107216896
#define WS_END       207880192

typedef __attribute__((ext_vector_type(8))) short short8;
typedef __attribute__((ext_vector_type(4))) short short4v;
typedef __attribute__((ext_vector_type(4))) float f32x4;

__device__ __forceinline__ unsigned short bf16_rne(float v){
    unsigned u = __float_as_uint(v);
    return (unsigned short)((u + 0x7FFFu + ((u >> 16) & 1u)) >> 16);
}
__device__ __forceinline__ void split2(float v, unsigned short& h, unsigned short& l){
    h = bf16_rne(v);
    float hf = __uint_as_float(((unsigned)h) << 16);
    l = bf16_rne(v - hf);
}

__device__ __forceinline__ void fma4(float4& a, float w, const float4& v){
    a.x = fmaf(w, v.x, a.x); a.y = fmaf(w, v.y, a.y);
    a.z = fmaf(w, v.z, a.z); a.w = fmaf(w, v.w, a.w);
}

__global__ __launch_bounds__(256) void k_zero(int* __restrict__ p, int v, int n){
    int i = blockIdx.x*256 + threadIdx.x;
    if (i < n) p[i] = v;
}

__global__ __launch_bounds__(256) void k_copy(const float4* __restrict__ in,
                                              float4* __restrict__ out, int n4){
    int stride = gridDim.x*256;
    for (int i = blockIdx.x*256 + threadIdx.x; i < n4; i += stride) out[i] = in[i];
}

__global__ __launch_bounds__(256) void k_count(const int* __restrict__ eie,
                                               const int* __restrict__ ein,
                                               int* __restrict__ counts){
    int gi = blockIdx.z; int g = gi >> 2, b = gi & 3;
    const int* dst = (g ? ein : eie) + ((size_t)b*2 + 1)*EG;
    int* c = counts + gi*NSUB;
    for (int e = blockIdx.x*256 + threadIdx.x; e < EG; e += gridDim.x*256)
        atomicAdd(&c[dst[e]], 1);
}

__global__ __launch_bounds__(256) void k_scan(const int* __restrict__ counts,
                                              int* __restrict__ offsets,
                                              int* __restrict__ pos,
                                              float* __restrict__ dinv){
    int gi = blockIdx.x;
    int t  = threadIdx.x;
    __shared__ int part[256];
    const int* c = counts + gi*NSUB;
    int loc[16]; int s = 0;
    int base = t*16;
    #pragma unroll
    for (int j=0;j<16;j++){ loc[j] = s; s += c[base+j]; }
    part[t] = s;
    __syncthreads();
    for (int off=1; off<256; off<<=1){
        int v = 0;
        if (t >= off) v = part[t-off];
        __syncthreads();
        if (t >= off) part[t] += v;
        __syncthreads();
    }
    int prefix = (t==0) ? 0 : part[t-1];
    #pragma unroll
    for (int j=0;j<16;j++){
        int o = prefix + loc[j];
        offsets[gi*NSUB + base + j] = o;
        pos[gi*NSUB + base + j]     = o;
        dinv[gi*NSUB + base + j]    = 1.0f / sqrtf((float)(c[base+j] + 1));
    }
}

__global__ __launch_bounds__(256) void k_fill(const int* __restrict__ eie,
                                              const int* __restrict__ ein,
                                              int* __restrict__ pos,
                                              int* __restrict__ csr){
    int gi = blockIdx.z; int g = gi >> 2, b = gi & 3;
    const int* ei = (g ? ein : eie) + (size_t)b*2*EG;
    int* p  = pos + gi*NSUB;
    int* cs = csr + (size_t)gi*EG;
    for (int e = blockIdx.x*256 + threadIdx.x; e < EG; e += gridDim.x*256){
        int src = ei[e], d = ei[EG + e];
        int q = atomicAdd(&p[d], 1);
        cs[q] = src;
    }
}

__global__ __launch_bounds__(256) void k_inv(const int* __restrict__ e2t,
                                             const int* __restrict__ n2t,
                                             int* __restrict__ inv){
    int gi = blockIdx.z; int g = gi >> 2, b = gi & 3;
    const int* omap = (g ? n2t : e2t) + b*NSUB;
    int i = blockIdx.x*256 + threadIdx.x;
    if (i < NSUB) inv[(size_t)gi*Sn + omap[i]] = i;
}

__global__ __launch_bounds__(256) void k_wsplit(const float* __restrict__ We,
                                                const float* __restrict__ Wn,
                                                unsigned short* __restrict__ WT){
    __shared__ float tile[32][33];
    int g = blockIdx.z;
    const float* W = g ? Wn : We;
    int k0 = blockIdx.x*32, n0 = blockIdx.y*32;
    int tx = threadIdx.x & 31, ty = threadIdx.x >> 5;
    for (int r = ty; r < 32; r += 8) tile[r][tx] = W[(size_t)(k0 + r)*Dn + n0 + tx];
    __syncthreads();
    unsigned short* hi = WT + (size_t)g*2*Dn*Dn;
    unsigned short* lo = hi + (size_t)Dn*Dn;
    for (int r = ty; r < 32; r += 8){
        float v = tile[tx][r];
        unsigned short h, l;
        split2(v, h, l);
        hi[(size_t)(n0 + r)*Dn + k0 + tx] = h;
        lo[(size_t)(n0 + r)*Dn + k0 + tx] = l;
    }
}

// split-bf16 3-pass MFMA GEMM (unchanged; ~760 TF effective)
__global__ __launch_bounds__(256) void k_gemm(const float* __restrict__ T,
                                              const int* __restrict__ t2e,
                                              const int* __restrict__ t2n,
                                              const unsigned short* __restrict__ WT,
                                              float* __restrict__ xw, int gi0){
    int z = blockIdx.z; int gi = gi0 + z;
    int g = gi >> 2, b = gi & 3;
    const int*   map = (g ? t2n : t2e) + b*NSUB;
    const float* X   = T + (size_t)b*Sn*Dn;
    const unsigned short* WTh = WT + (size_t)g*2*Dn*Dn;
    const unsigned short* WTl = WTh + (size_t)Dn*Dn;
    float* O = xw + (size_t)z*NSUB*Dn;

    __shared__ unsigned short AsH[128*32], AsL[128*32], BsH[128*32], BsL[128*32];
    __shared__ int rows[128];

    int bm = blockIdx.x*128, bn = blockIdx.y*128;
    int tid = threadIdx.x;
    if (tid < 128) rows[tid] = map[bm + tid];
    __syncthreads();

    int lane = tid & 63, wid = tid >> 6;
    int wm = (wid >> 1)*64, wn = (wid & 1)*64;

    const float* aptr[4]; int aidx[4];
    #pragma unroll
    for (int l=0;l<4;l++){
        int lin = tid + l*256;
        int row = lin >> 3, f = lin & 7;
        aptr[l] = X + (size_t)rows[row]*Dn + f*4;
        int c = f >> 1, cp = c ^ ((row >> 1) & 3);
        aidx[l] = row*32 + cp*8 + (f&1)*4;
    }
    int bsrc[2], bdst[2];
    #pragma unroll
    for (int l=0;l<2;l++){
        int ci = tid + l*256;
        int n = ci >> 2, c = ci & 3;
        int cp = c ^ ((n >> 1) & 3);
        bsrc[l] = (bn + n)*Dn + c*8;
        bdst[l] = n*32 + cp*8;
    }
    int aoff[4], boff[4];
    int kc = lane >> 4;
    #pragma unroll
    for (int mt=0; mt<4; mt++){
        int r = wm + mt*16 + (lane & 15);
        aoff[mt] = r*32 + (kc ^ ((r >> 1) & 3))*8;
    }
    #pragma unroll
    for (int nt=0; nt<4; nt++){
        int cn = wn + nt*16 + (lane & 15);
        boff[nt] = cn*32 + (kc ^ ((cn >> 1) & 3))*8;
    }

    f32x4 acc[4][4];
    #pragma unroll
    for (int i=0;i<4;i++)
        #pragma unroll
        for (int j=0;j<4;j++)
            acc[i][j] = f32x4{0.f,0.f,0.f,0.f};

    for (int k0 = 0; k0 < Dn; k0 += 32){
        #pragma unroll
        for (int l=0;l<4;l++){
            float4 v = *(const float4*)(aptr[l] + k0);
            short4v h, lo;
            unsigned short hh, ll;
            split2(v.x, hh, ll); h.x = (short)hh; lo.x = (short)ll;
            split2(v.y, hh, ll); h.y = (short)hh; lo.y = (short)ll;
            split2(v.z, hh, ll); h.z = (short)hh; lo.z = (short)ll;
            split2(v.w, hh, ll); h.w = (short)hh; lo.w = (short)ll;
            *(short4v*)&AsH[aidx[l]] = h;
            *(short4v*)&AsL[aidx[l]] = lo;
        }
        #pragma unroll
        for (int l=0;l<2;l++){
            *(short8*)&BsH[bdst[l]] = *(const short8*)&WTh[bsrc[l] + k0];
            *(short8*)&BsL[bdst[l]] = *(const short8*)&WTl[bsrc[l] + k0];
        }
        __syncthreads();

        short8 ah[4], al[4];
        #pragma unroll
        for (int mt=0; mt<4; mt++){
            ah[mt] = *(const short8*)&AsH[aoff[mt]];
            al[mt] = *(const short8*)&AsL[aoff[mt]];
        }
        #pragma unroll
        for (int nt=0; nt<4; nt++){
            short8 bh = *(const short8*)&BsH[boff[nt]];
            short8 bl = *(const short8*)&BsL[boff[nt]];
            #pragma unroll
            for (int mt=0; mt<4; mt++){
                acc[mt][nt] = __builtin_amdgcn_mfma_f32_16x16x32_bf16(ah[mt], bh, acc[mt][nt], 0, 0, 0);
                acc[mt][nt] = __builtin_amdgcn_mfma_f32_16x16x32_bf16(al[mt], bh, acc[mt][nt], 0, 0, 0);
                acc[mt][nt] = __builtin_amdgcn_mfma_f32_16x16x32_bf16(ah[mt], bl, acc[mt][nt], 0, 0, 0);
            }
        }
        __syncthreads();
    }

    int r0 = (lane >> 4)*4, cc = lane & 15;
    #pragma unroll
    for (int mt=0; mt<4; mt++){
        #pragma unroll
        for (int j=0; j<4; j++){
            int row = bm + wm + mt*16 + r0 + j;
            float* orow = O + (size_t)row*Dn + bn + wn + cc;
            #pragma unroll
            for (int nt=0; nt<4; nt++) orow[nt*16] = acc[mt][nt][j];
        }
    }
}

// legacy RMW agg for fallback tiers
__global__ __launch_bounds__(256) void k_agg(const int* __restrict__ csr,
                                             const int* __restrict__ offsets,
                                             const float* __restrict__ dinv,
                                             const float* __restrict__ xw,
                                             const float* __restrict__ be,
                                             const float* __restrict__ bn_,
                                             const int* __restrict__ e2t,
                                             const int* __restrict__ n2t,
                                             const float* __restrict__ ga,
                                             const float* __restrict__ gb,
                                             float* __restrict__ out,
                                             int g, int b0, int slot0){
    int zb = blockIdx.z;
    int b  = b0 + zb;
    int gi = g*4 + b;
    int slot = slot0 + zb;
    int wave = threadIdx.x >> 6, lane = threadIdx.x & 63;
    int i = blockIdx.x*4 + wave;
    const float* bias = g ? bn_ : be;
    float gate = tanhf(g ? gb[0] : ga[0]);
    const float* xws = xw + (size_t)slot*NSUB*Dn;
    const float* dv  = dinv + gi*NSUB;
    const int*   cs  = csr + (size_t)gi*EG;

    int start = offsets[gi*NSUB + i];
    int end   = (i == NSUB-1) ? EG : offsets[gi*NSUB + i + 1];
    float di  = dv[i];

    const float4* xr = (const float4*)(xws + (size_t)i*Dn);
    float4 a0 = xr[lane], a1 = xr[64+lane], a2 = xr[128+lane];
    float4 acc0 = make_float4(di*a0.x, di*a0.y, di*a0.z, di*a0.w);
    float4 acc1 = make_float4(di*a1.x, di*a1.y, di*a1.z, di*a1.w);
    float4 acc2 = make_float4(di*a2.x, di*a2.y, di*a2.z, di*a2.w);

    for (int e = start; e < end; e++){
        int src = cs[e];
        float w = dv[src];
        const float4* xs = (const float4*)(xws + (size_t)src*Dn);
        fma4(acc0, w, xs[lane]);
        fma4(acc1, w, xs[64+lane]);
        fma4(acc2, w, xs[128+lane]);
    }

    const float4* bi = (const float4*)bias;
    float4 b0v = bi[lane], b1v = bi[64+lane], b2v = bi[128+lane];

    const int* omap = (g ? n2t : e2t) + b*NSUB;
    int tok = omap[i];
    float4* o = (float4*)(out + ((size_t)b*Sn + tok)*Dn);
    float4 c0 = o[lane], c1 = o[64+lane], c2 = o[128+lane];
    o[lane]     = make_float4(c0.x + gate*(di*acc0.x+b0v.x), c0.y + gate*(di*acc0.y+b0v.y),
                              c0.z + gate*(di*acc0.z+b0v.z), c0.w + gate*(di*acc0.w+b0v.w));
    o[64+lane]  = make_float4(c1.x + gate*(di*acc1.x+b1v.x), c1.y + gate*(di*acc1.y+b1v.y),
                              c1.z + gate*(di*acc1.z+b1v.z), c1.w + gate*(di*acc1.w+b1v.w));
    o[128+lane] = make_float4(c2.x + gate*(di*acc2.x+b2v.x), c2.y + gate*(di*acc2.y+b2v.y),
                              c2.z + gate*(di*acc2.z+b2v.z), c2.w + gate*(di*acc2.w+b2v.w));
}

// L2-resident column-chunked aggregation.
// grid = 49152 1D blocks: gi = bid&7 (XCD affinity), j = bid>>3,
// chunk = j>>10 (6 x 128 cols), rowblk = j&1023. Wave = one dst row x 128 cols.
// Working set per (graph,chunk) = 4096x128x4B = 2MB -> XCD L2 resident, ~9x reuse.
__global__ __launch_bounds__(256) void k_agg2(const int* __restrict__ csr,
                                              const int* __restrict__ offsets,
                                              const float* __restrict__ dinv,
                                              const float* __restrict__ xw,
                                              const float* __restrict__ be,
                                              const float* __restrict__ bn_,
                                              const float* __restrict__ ga,
                                              const float* __restrict__ gb,
                                              float* __restrict__ emb){
    int bid = blockIdx.x;
    int gi = bid & 7;
    int j = bid >> 3;
    int chunk = j >> 10;
    int rblk = j & 1023;
    int g = gi >> 2;
    int wid = threadIdx.x >> 6, lane = threadIdx.x & 63;
    int i = rblk*4 + wid;

    const float* bias = g ? bn_ : be;
    float gate = tanhf(g ? gb[0] : ga[0]);
    const float* xws = xw + (size_t)gi*NSUB*Dn;
    const float* dv  = dinv + gi*NSUB;
    const int*   cs  = csr + (size_t)gi*EG;

    int start = offsets[gi*NSUB + i];
    int end   = (i == NSUB-1) ? EG : offsets[gi*NSUB + i + 1];
    float di  = dv[i];

    int c2 = chunk*64 + lane;          // float2 index within row

    const float2* xr = (const float2*)(xws + (size_t)i*Dn);
    float2 a = xr[c2];
    float ax = di*a.x, ay = di*a.y;

    int e = start;
    for (; e + 4 <= end; e += 4){
        int s0 = cs[e], s1 = cs[e+1], s2 = cs[e+2], s3 = cs[e+3];
        float w0 = dv[s0], w1 = dv[s1], w2 = dv[s2], w3 = dv[s3];
        float2 v0 = ((const float2*)(xws + (size_t)s0*Dn))[c2];
        float2 v1 = ((const float2*)(xws + (size_t)s1*Dn))[c2];
        float2 v2 = ((const float2*)(xws + (size_t)s2*Dn))[c2];
        float2 v3 = ((const float2*)(xws + (size_t)s3*Dn))[c2];
        ax = fmaf(w0, v0.x, ax); ay = fmaf(w0, v0.y, ay);
        ax = fmaf(w1, v1.x, ax); ay = fmaf(w1, v1.y, ay);
        ax = fmaf(w2, v2.x, ax); ay = fmaf(w2, v2.y, ay);
        ax = fmaf(w3, v3.x, ax); ay = fmaf(w3, v3.y, ay);
    }
    for (; e < end; e++){
        int src = cs[e];
        float w = dv[src];
        float2 v = ((const float2*)(xws + (size_t)src*Dn))[c2];
        ax = fmaf(w, v.x, ax); ay = fmaf(w, v.y, ay);
    }

    float2 bv = ((const float2*)bias)[c2];
    float2 r;
    r.x = gate*(di*ax + bv.x);
    r.y = gate*(di*ay + bv.y);
    ((float2*)(emb + ((size_t)gi*NSUB + i)*Dn))[c2] = r;
}

// out[b][tok] = T[b][tok] + emb_e[inv_e] + emb_n[inv_n]   (emb pre-gated+biased)
__global__ __launch_bounds__(256) void k_fuse(const float* __restrict__ T,
                                              const int* __restrict__ inv,
                                              const float* __restrict__ emb,
                                              float* __restrict__ out){
    int wave = threadIdx.x >> 6, lane = threadIdx.x & 63;
    int row = blockIdx.x*4 + wave;
    int b = row >> 13, tok = row & (Sn-1);

    const float4* tr = (const float4*)(T + (size_t)row*Dn);
    float4 t0 = tr[lane], t1 = tr[64+lane], t2 = tr[128+lane];

    int ie = inv[(size_t)b*Sn + tok];
    int in_ = inv[(size_t)(4+b)*Sn + tok];
    if (ie >= 0){
        const float4* er = (const float4*)(emb + ((size_t)b*NSUB + ie)*Dn);
        float4 e0 = er[lane], e1 = er[64+lane], e2 = er[128+lane];
        t0.x += e0.x; t0.y += e0.y; t0.z += e0.z; t0.w += e0.w;
        t1.x += e1.x; t1.y += e1.y; t1.z += e1.z; t1.w += e1.w;
        t2.x += e2.x; t2.y += e2.y; t2.z += e2.z; t2.w += e2.w;
    }
    if (in_ >= 0){
        const float4* er = (const float4*)(emb + ((size_t)(4+b)*NSUB + in_)*Dn);
        float4 e0 = er[lane], e1 = er[64+lane], e2 = er[128+lane];
        t0.x += e0.x; t0.y += e0.y; t0.z += e0.z; t0.w += e0.w;
        t1.x += e1.x; t1.y += e1.y; t1.z += e1.z; t1.w += e1.w;
        t2.x += e2.x; t2.y += e2.y; t2.z += e2.z; t2.w += e2.w;
    }
    float4* o = (float4*)(out + (size_t)row*Dn);
    o[lane] = t0; o[64+lane] = t1; o[128+lane] = t2;
}

extern "C" void kernel_launch(void* const* d_in, const int* in_sizes, int n_in,
                              void* d_out, int out_size, void* d_ws, size_t ws_size,
                              hipStream_t stream){
    const float* T   = (const float*)d_in[0];
    const int*   t2e = (const int*)d_in[1];
    const int*   e2t = (const int*)d_in[2];
    const int*   t2n = (const int*)d_in[3];
    const int*   n2t = (const int*)d_in[4];
    const int*   eie = (const int*)d_in[5];
    const int*   ein = (const int*)d_in[6];
    const float* We  = (const float*)d_in[7];
    const float* be  = (const float*)d_in[8];
    const float* Wn  = (const float*)d_in[9];
    const float* bnn = (const float*)d_in[10];
    const float* ga  = (const float*)d_in[11];
    const float* gb  = (const float*)d_in[12];
    float* out = (float*)d_out;

    char* ws = (char*)d_ws;
    int*   counts  = (int*)(ws + OFF_COUNTS);
    int*   offsets = (int*)(ws + OFF_OFFSETS);
    int*   pos     = (int*)(ws + OFF_POS);
    float* dinv    = (float*)(ws + OFF_DINV);
    int*   csr     = (int*)(ws + OFF_CSR);
    int*   inv     = (int*)(ws + OFF_INV);
    unsigned short* WT = (unsigned short*)(ws + OFF_WT);
    float* xw      = (float*)(ws + OFF_XW);
    float* emb     = (float*)(ws + OFF_EMB);

    size_t xw_slot = (size_t)NSUB*Dn*4;
    bool tier2 = ws_size >= (size_t)WS_END;
    bool tier1 = ws_size >= (size_t)OFF_XW + 8*xw_slot;

    k_zero<<<dim3((8*NSUB+255)/256), 256, 0, stream>>>(counts, 0, 8*NSUB);
    k_count<<<dim3(32,1,8), 256, 0, stream>>>(eie, ein, counts);
    k_wsplit<<<dim3(24,24,2), 256, 0, stream>>>(We, Wn, WT);
    k_scan<<<dim3(8), 256, 0, stream>>>(counts, offsets, pos, dinv);
    k_fill<<<dim3(32,1,8), 256, 0, stream>>>(eie, ein, pos, csr);

    if (tier2){
        k_zero<<<dim3((8*Sn+255)/256), 256, 0, stream>>>(inv, -1, 8*Sn);
        k_inv<<<dim3(16,1,8), 256, 0, stream>>>(e2t, n2t, inv);
        k_gemm<<<dim3(32,6,8), 256, 0, stream>>>(T, t2e, t2n, WT, xw, 0);
        k_agg2<<<dim3(49152), 256, 0, stream>>>(csr, offsets, dinv, xw, be, bnn,
                                                ga, gb, emb);
        k_fuse<<<dim3(Bn*Sn/4), 256, 0, stream>>>(T, inv, emb, out);
    } else if (tier1){
        int n4 = Bn*Sn*Dn/4;
        k_copy<<<dim3(2048), 256, 0, stream>>>((const float4*)T, (float4*)out, n4);
        k_gemm<<<dim3(32,6,8), 256, 0, stream>>>(T, t2e, t2n, WT, xw, 0);
        k_agg<<<dim3(1024,1,4), 256, 0, stream>>>(csr, offsets, dinv, xw, be, bnn,
                                                  e2t, n2t, ga, gb, out, 0, 0, 0);
        k_agg<<<dim3(1024,1,4), 256, 0, stream>>>(csr, offsets, dinv, xw, be, bnn,
                                                  e2t, n2t, ga, gb, out, 1, 0, 4);
    } else {
        int n4 = Bn*Sn*Dn/4;
        k_copy<<<dim3(2048), 256, 0, stream>>>((const float4*)T, (float4*)out, n4);
        for (int gi = 0; gi < 8; ++gi){
            k_gemm<<<dim3(32,6,1), 256, 0, stream>>>(T, t2e, t2n, WT, xw, gi);
            k_agg<<<dim3(1024,1,1), 256, 0, stream>>>(csr, offsets, dinv, xw, be, bnn,
                                                      e2t, n2t, ga, gb, out, gi>>2, gi&3, 0);
        }
    }
}